// Round 5
// baseline (149.535 us; speedup 1.0000x reference)
//
#include <hip/hip_runtime.h>

// NonImagingRod: per-ray damped-Newton (LM) root find on f(t) = A t^2 + B t + C.
// Round-14: R9's 4-chunk software pipeline x R13's strided-float3 coalescing.
// R13 post-mortem: strided ray->lane map + float3 loads WORKED -- rod_kernel
// dropped below the ~40us poison fills (was 42-44us; now <39, est ~37).
// Coalescing theory confirmed: blocked AoS float4 cost ~3x compulsory lines.
// Remaining gap vs floor (~20us VALU issue + ~15us HBM, overlapped => 22-25):
// R13 loads ALL data up front; all waves' requests interleave ~FIFO, so every
// wave's last load lands at ~T_mem and compute starts only then -> additive
// wall ~ T_mem + T_compute ~ 37us. Fix: re-introduce the R8/R9-proven
// intra-thread pipeline (prefetch chunk k+1 before iterate chunk k) so 3/4 of
// delivery hides under compute. 16 rays/thread = 4 chunks x 4 strided rays.
//
// Predicted: rod 24-29us, VALUBusy 55-70%, FETCH ~49-50MB, VGPR 64-84 (fine:
// 1024 blocks = 4 blocks/CU = 4 waves/SIMD needs <=128 VGPR). absmax 0.0.
// If FLAT vs R13: pipelining can't overlap the coalesced stream; next lever
// is shrinking the compute term (VALU ops/iter) or declare floor.
//
// Codegen notes (hard-won, R2-R13):
//  - scalar iterate (4 fma + 2 mul + 1 rcp per ray) is the proven shape;
//    packed v2f neutral (no double-rate fp32 pk on gfx950 -- 157TF = wave64
//    FMA rate). DMA global_load_lds staging serialized MLP and lost 50%.
//  - No-spill signature: FETCH_SIZE stable ~49-50 MB.
//  - Clamp(+-1000) provably inactive; rcp ~1ulp fine (absmax 0.0, R2-R13).
//  - f64 accumulate -> wave shuffle -> LDS -> one atomic/block: absmax 0.0
//    across all grouping changes.

#define LM_ITERS 31
constexpr float DAMPING = 0.5f;

struct F3 { float x, y, z; };   // 12B, 4-aligned -> global_load_dwordx3

struct Rays4 { float px[4], py[4], pz[4], vx[4], vy[4], vz[4]; };

__global__ __launch_bounds__(256) void rod_kernel(
    const float* __restrict__ P, const float* __restrict__ V,
    const float* __restrict__ Rm, const float* __restrict__ Tv,
    const float* __restrict__ c_ptr, double* __restrict__ ws, int n)
{
    const float c  = c_ptr[0];
    const float r00 = Rm[0], r01 = Rm[1], r02 = Rm[2];
    const float r10 = Rm[3], r11 = Rm[4], r12 = Rm[5];
    const float r20 = Rm[6], r21 = Rm[7], r22 = Rm[8];
    const float t0 = Tv[0], t1 = Tv[1], t2 = Tv[2];

    const int lane = threadIdx.x & 63;
    const int wave = threadIdx.x >> 6;
    // wave owns 1024 consecutive rays as 4 chunks of 256; within a chunk,
    // lane's 4 rays are strided (64*r + lane) so every load instruction reads
    // a 768B lane-contiguous window (perfect coalescing, R13-proven).
    const int wbase = (blockIdx.x * 4 + wave) * 1024;

    const F3* __restrict__ P3 = (const F3*)P;
    const F3* __restrict__ V3 = (const F3*)V;

    // ---- coalesced chunk load: 8 x dwordx3, all in flight together ----
    auto load4 = [&](int cbase) -> Rays4 {
        Rays4 q;
        if (cbase + 256 <= n) {
            #pragma unroll
            for (int r = 0; r < 4; ++r) {
                const F3 p = P3[cbase + 64 * r + lane];
                q.px[r] = p.x; q.py[r] = p.y; q.pz[r] = p.z;
            }
            #pragma unroll
            for (int r = 0; r < 4; ++r) {
                const F3 v = V3[cbase + 64 * r + lane];
                q.vx[r] = v.x; q.vy[r] = v.y; q.vz[r] = v.z;
            }
        } else {
            #pragma unroll
            for (int r = 0; r < 4; ++r) {
                const int ray = cbase + 64 * r + lane;
                if (ray < n) {
                    q.px[r] = P[3 * ray + 0]; q.py[r] = P[3 * ray + 1]; q.pz[r] = P[3 * ray + 2];
                    q.vx[r] = V[3 * ray + 0]; q.vy[r] = V[3 * ray + 1]; q.vz[r] = V[3 * ray + 2];
                } else {
                    q.px[r] = q.py[r] = q.pz[r] = 0.0f;
                    q.vx[r] = q.vy[r] = q.vz[r] = 0.0f;
                }
            }
        }
        return q;
    };

    float nA[4], f[4], fp[4];

    // rigid inverse transform + quadratic coefficients for 4 rays
    auto setup4 = [&](const Rays4& q) {
        #pragma unroll
        for (int r = 0; r < 4; ++r) {
            const float ax = q.px[r] - t0, ay = q.py[r] - t1, az = q.pz[r] - t2;
            const float plx = ax * r00 + ay * r10 + az * r20;
            const float ply = ax * r01 + ay * r11 + az * r21;
            const float plz = ax * r02 + ay * r12 + az * r22;
            const float vlx = q.vx[r] * r00 + q.vy[r] * r10 + q.vz[r] * r20;
            const float vly = q.vx[r] * r01 + q.vy[r] * r11 + q.vz[r] * r21;
            const float vlz = q.vx[r] * r02 + q.vy[r] * r12 + q.vz[r] * r22;
            nA[r] = c * (vly * vly + vlz * vlz);                 // -A
            f[r]  = plx - c * (ply * ply + plz * plz);           // f(0)  = C
            fp[r] = vlx - 2.0f * c * (ply * vly + plz * vlz);    // f'(0) = B
        }
    };

    // delta = f*f'/(f'^2+damping); tmp = f' - A*delta;
    // f <- f - delta*tmp (exact quadratic); f' <- tmp - A*delta.
    auto iterate = [&]() {
        #pragma unroll 1
        for (int it = 0; it < LM_ITERS; ++it) {
            #pragma unroll
            for (int r = 0; r < 4; ++r) {
                const float den = fmaf(fp[r], fp[r], DAMPING);
                const float rcp = __builtin_amdgcn_rcpf(den);  // ~1 ulp; LM self-corrects
                const float d   = (f[r] * fp[r]) * rcp;
                const float tmp = fmaf(nA[r], d, fp[r]);
                f[r]  = fmaf(-d, tmp, f[r]);
                fp[r] = fmaf(nA[r], d, tmp);
            }
        }
    };

    double acc = 0.0;
    auto accum = [&](int cbase) {
        #pragma unroll
        for (int r = 0; r < 4; ++r)
            if (cbase + 64 * r + lane < n) acc += (double)f[r] * (double)f[r];
    };

    const int c0 = wbase, c1 = wbase + 256, c2 = wbase + 512, c3 = wbase + 768;

    // ---- 4-stage software pipeline: prefetch k+1 before iterate k ----
    Rays4 q0 = load4(c0);
    setup4(q0);
    Rays4 q1 = load4(c1);          // in flight during iterate(c0)
    iterate();
    accum(c0);

    setup4(q1);                    // waits on q1 loads (long since landed)
    Rays4 q2 = load4(c2);          // in flight during iterate(c1)
    iterate();
    accum(c1);

    setup4(q2);
    Rays4 q3 = load4(c3);          // in flight during iterate(c2)
    iterate();
    accum(c2);

    setup4(q3);
    iterate();
    accum(c3);

    // wave(64) shuffle reduce -> LDS across 4 waves -> one f64 atomic per block
    for (int off = 32; off > 0; off >>= 1)
        acc += __shfl_down(acc, off, 64);
    __shared__ double sacc[4];
    if (lane == 0) sacc[wave] = acc;
    __syncthreads();
    if (threadIdx.x == 0) {
        atomicAdd(ws, sacc[0] + sacc[1] + sacc[2] + sacc[3]);
    }
}

__global__ void rod_finalize(const double* __restrict__ ws,
                             const float* __restrict__ loss_in,
                             float* __restrict__ out, double inv_n)
{
    out[0] = (float)(ws[0] * inv_n + (double)loss_in[0]);
}

extern "C" void kernel_launch(void* const* d_in, const int* in_sizes, int n_in,
                              void* d_out, int out_size, void* d_ws, size_t ws_size,
                              hipStream_t stream) {
    const float* P       = (const float*)d_in[0];
    const float* V       = (const float*)d_in[1];
    const float* R       = (const float*)d_in[2];
    const float* T       = (const float*)d_in[3];
    const float* c       = (const float*)d_in[4];
    const float* loss_in = (const float*)d_in[5];

    const int n = in_sizes[0] / 3;           // number of rays

    // d_ws is poisoned to 0xAA before every launch — zero the accumulator.
    hipMemsetAsync(d_ws, 0, sizeof(double), stream);

    // 16 rays/thread = 4 pipelined chunks of 4 strided rays.
    // 1024 blocks = 4 blocks/CU, whole grid co-resident in one round.
    const int threads = (n + 15) / 16;
    const int block   = 256;
    const int grid    = (threads + block - 1) / block;
    rod_kernel<<<grid, block, 0, stream>>>(P, V, R, T, c, (double*)d_ws, n);
    rod_finalize<<<1, 1, 0, stream>>>((const double*)d_ws, loss_in,
                                      (float*)d_out, 1.0 / (double)n);
}

// Round 6
// 142.884 us; speedup vs baseline: 1.0465x; 1.0465x over previous
//
#include <hip/hip_runtime.h>

// NonImagingRod: per-ray damped-Newton (LM) root find on f(t) = A t^2 + B t + C.
// Round-15: R14's plan (strided-float3 coalescing x 4-chunk pipeline), fixed.
// R14 post-mortem: WRITE_SIZE exploded 64B -> 24.6MB = SPILL. The Rays4
// struct returned by value from a branchy lambda was not SROA'd -> alloca ->
// every prefetch round-tripped scratch (VGPR stuck at 48, first dispatch
// 146us = scratch warm-up). Classic aggregate-state-to-local-memory hazard.
// Fix: identical schedule, but ALL pipeline state in named F3 scalars with
// two alternating register sets (A/B) -- the R9-proven clean shape -- and
// per-ray setup through fixed-index 4-arrays only.
//
// Model (stable across R8-R14): wall = T_mem + T_compute additive when loads
// aren't pipelined; T_compute ~ 20us VALU issue (invariant), T_mem ~ 15us at
// the coalesced-compulsory floor (R13 proved the strided-float3 pattern).
// Pipelined: first-chunk exposure + max(...) ~ 25-30us.
//
// Predicted: WRITE_SIZE back to ~64-128B + FETCH ~49-50MB (spill gone; THE
// verification), VGPR 60-90, rod 26-32us, VALUBusy 55-70%, absmax 0.0.
// If spill-free but FLAT vs R13 (~37us): intra-thread prefetch can't overlap
// this stream; next = shrink VALU term or declare floor.
//
// Codegen notes (hard-won, R2-R14):
//  - NEVER return aggregates from branchy lambdas / hold pipeline state in
//    structs: alloca -> scratch (R14, 24MB writes). Named scalars only.
//  - scalar iterate (4 fma + 2 mul + 1 rcp per ray) is the proven shape;
//    packed v2f neutral (no double-rate fp32 on gfx950).
//  - global_load_lds staging serialized MLP, lost 50% (R12).
//  - No-spill signature: FETCH ~49-50MB, WRITE ~64-128B.
//  - Clamp(+-1000) provably inactive; rcp ~1ulp fine (absmax 0.0, R2-R14).

#define LM_ITERS 31
constexpr float DAMPING = 0.5f;

struct F3 { float x, y, z; };   // 12B, 4-aligned -> global_load_dwordx3

__global__ __launch_bounds__(256, 4) void rod_kernel(
    const float* __restrict__ P, const float* __restrict__ V,
    const float* __restrict__ Rm, const float* __restrict__ Tv,
    const float* __restrict__ c_ptr, double* __restrict__ ws, int n)
{
    const float c  = c_ptr[0];
    const float r00 = Rm[0], r01 = Rm[1], r02 = Rm[2];
    const float r10 = Rm[3], r11 = Rm[4], r12 = Rm[5];
    const float r20 = Rm[6], r21 = Rm[7], r22 = Rm[8];
    const float t0 = Tv[0], t1 = Tv[1], t2 = Tv[2];

    const int lane = threadIdx.x & 63;
    const int wave = threadIdx.x >> 6;
    // wave owns 1024 consecutive rays as 4 chunks of 256; within a chunk,
    // lane's 4 rays are strided (cbase + 64*r + lane): every load instruction
    // reads a 768B lane-contiguous window (perfect coalescing, R13-proven).
    const int wbase = (blockIdx.x * 4 + wave) * 1024;

    const F3* __restrict__ P3 = (const F3*)P;
    const F3* __restrict__ V3 = (const F3*)V;

    // guarded single-ray loads (tail only; n=4M never takes the zero path)
    auto ldP = [&](int ray) -> F3 {
        if (ray < n) return P3[ray];
        F3 z; z.x = 0.0f; z.y = 0.0f; z.z = 0.0f; return z;
    };
    auto ldV = [&](int ray) -> F3 {
        if (ray < n) return V3[ray];
        F3 z; z.x = 0.0f; z.y = 0.0f; z.z = 0.0f; return z;
    };

    float nA[4], f[4], fp[4];

    // rigid inverse transform + quadratic coefficients, one ray -> slot r
    auto setup1 = [&](const F3& p, const F3& v, int r) {
        const float ax = p.x - t0, ay = p.y - t1, az = p.z - t2;
        const float plx = ax * r00 + ay * r10 + az * r20;
        const float ply = ax * r01 + ay * r11 + az * r21;
        const float plz = ax * r02 + ay * r12 + az * r22;
        const float vlx = v.x * r00 + v.y * r10 + v.z * r20;
        const float vly = v.x * r01 + v.y * r11 + v.z * r21;
        const float vlz = v.x * r02 + v.y * r12 + v.z * r22;
        nA[r] = c * (vly * vly + vlz * vlz);                 // -A
        f[r]  = plx - c * (ply * ply + plz * plz);           // f(0)  = C
        fp[r] = vlx - 2.0f * c * (ply * vly + plz * vlz);    // f'(0) = B
    };

    // delta = f*f'/(f'^2+damping); tmp = f' - A*delta;
    // f <- f - delta*tmp (exact quadratic); f' <- tmp - A*delta.
    auto iterate = [&]() {
        #pragma unroll 1
        for (int it = 0; it < LM_ITERS; ++it) {
            #pragma unroll
            for (int r = 0; r < 4; ++r) {
                const float den = fmaf(fp[r], fp[r], DAMPING);
                const float rcp = __builtin_amdgcn_rcpf(den);  // ~1 ulp; LM self-corrects
                const float d   = (f[r] * fp[r]) * rcp;
                const float tmp = fmaf(nA[r], d, fp[r]);
                f[r]  = fmaf(-d, tmp, f[r]);
                fp[r] = fmaf(nA[r], d, tmp);
            }
        }
    };

    double acc = 0.0;
    auto accum = [&](int cbase) {
        #pragma unroll
        for (int r = 0; r < 4; ++r)
            if (cbase + 64 * r + lane < n) acc += (double)f[r] * (double)f[r];
    };

    const int c0 = wbase + lane;
    const int c1 = wbase + 256 + lane;
    const int c2 = wbase + 512 + lane;
    const int c3 = wbase + 768 + lane;

    // ---- 4-stage software pipeline, named-register A/B prefetch sets ----
    // chunk 0 -> set A
    F3 pA0 = ldP(c0), pA1 = ldP(c0 + 64), pA2 = ldP(c0 + 128), pA3 = ldP(c0 + 192);
    F3 vA0 = ldV(c0), vA1 = ldV(c0 + 64), vA2 = ldV(c0 + 128), vA3 = ldV(c0 + 192);
    setup1(pA0, vA0, 0); setup1(pA1, vA1, 1); setup1(pA2, vA2, 2); setup1(pA3, vA3, 3);

    // prefetch chunk 1 -> set B; iterate chunk 0
    F3 pB0 = ldP(c1), pB1 = ldP(c1 + 64), pB2 = ldP(c1 + 128), pB3 = ldP(c1 + 192);
    F3 vB0 = ldV(c1), vB1 = ldV(c1 + 64), vB2 = ldV(c1 + 128), vB3 = ldV(c1 + 192);
    iterate();
    accum(c0 - lane);

    // consume B; prefetch chunk 2 -> set A; iterate chunk 1
    setup1(pB0, vB0, 0); setup1(pB1, vB1, 1); setup1(pB2, vB2, 2); setup1(pB3, vB3, 3);
    pA0 = ldP(c2); pA1 = ldP(c2 + 64); pA2 = ldP(c2 + 128); pA3 = ldP(c2 + 192);
    vA0 = ldV(c2); vA1 = ldV(c2 + 64); vA2 = ldV(c2 + 128); vA3 = ldV(c2 + 192);
    iterate();
    accum(c1 - lane);

    // consume A; prefetch chunk 3 -> set B; iterate chunk 2
    setup1(pA0, vA0, 0); setup1(pA1, vA1, 1); setup1(pA2, vA2, 2); setup1(pA3, vA3, 3);
    pB0 = ldP(c3); pB1 = ldP(c3 + 64); pB2 = ldP(c3 + 128); pB3 = ldP(c3 + 192);
    vB0 = ldV(c3); vB1 = ldV(c3 + 64); vB2 = ldV(c3 + 128); vB3 = ldV(c3 + 192);
    iterate();
    accum(c2 - lane);

    // consume B; iterate chunk 3
    setup1(pB0, vB0, 0); setup1(pB1, vB1, 1); setup1(pB2, vB2, 2); setup1(pB3, vB3, 3);
    iterate();
    accum(c3 - lane);

    // wave(64) shuffle reduce -> LDS across 4 waves -> one f64 atomic per block
    for (int off = 32; off > 0; off >>= 1)
        acc += __shfl_down(acc, off, 64);
    __shared__ double sacc[4];
    if (lane == 0) sacc[wave] = acc;
    __syncthreads();
    if (threadIdx.x == 0) {
        atomicAdd(ws, sacc[0] + sacc[1] + sacc[2] + sacc[3]);
    }
}

__global__ void rod_finalize(const double* __restrict__ ws,
                             const float* __restrict__ loss_in,
                             float* __restrict__ out, double inv_n)
{
    out[0] = (float)(ws[0] * inv_n + (double)loss_in[0]);
}

extern "C" void kernel_launch(void* const* d_in, const int* in_sizes, int n_in,
                              void* d_out, int out_size, void* d_ws, size_t ws_size,
                              hipStream_t stream) {
    const float* P       = (const float*)d_in[0];
    const float* V       = (const float*)d_in[1];
    const float* R       = (const float*)d_in[2];
    const float* T       = (const float*)d_in[3];
    const float* c       = (const float*)d_in[4];
    const float* loss_in = (const float*)d_in[5];

    const int n = in_sizes[0] / 3;           // number of rays

    // d_ws is poisoned to 0xAA before every launch — zero the accumulator.
    hipMemsetAsync(d_ws, 0, sizeof(double), stream);

    // 16 rays/thread = 4 pipelined chunks of 4 strided rays.
    // 1024 blocks = 4 blocks/CU, whole grid co-resident in one round.
    const int threads = (n + 15) / 16;
    const int block   = 256;
    const int grid    = (threads + block - 1) / block;
    rod_kernel<<<grid, block, 0, stream>>>(P, V, R, T, c, (double*)d_ws, n);
    rod_finalize<<<1, 1, 0, stream>>>((const double*)d_ws, loss_in,
                                      (float*)d_out, 1.0 / (double)n);
}

// Round 7
// 139.019 us; speedup vs baseline: 1.0756x; 1.0278x over previous
//
#include <hip/hip_runtime.h>

// NonImagingRod: per-ray damped-Newton (LM) root find on f(t) = A t^2 + B t + C.
// Round-16: all-upfront chunk-ordered loads + CHUNKED CONSUMPTION.
// R15 post-mortem: spill fixed (WRITE 32B) but 46-50us, SLOWER than R13-flat
// (~37). VGPR=40 proves the 24 prefetch floats were never live across
// iterate(): the compiler SANK the between-phase loads to their consumers,
// serializing each chunk (full latency + setup + iterate). Both pipeline
// attempts died this way -- loads issued BETWEEN compute phases get sunk.
// Refined model: R13-flat is additive (wall ~ T_mem(14) + T_compute(19) ~ 37)
// because vmcnt retires in ISSUE ORDER and all waves' last load retires at
// ~T_mem; the single iterate-over-8-rays needs ALL data.
// Fix: keep R13's issue shape EXACTLY (all 16 loads at the top, nothing
// between them -> nothing to sink; max MLP), but in CHUNK ORDER, and split
// consumption into 4 chunks of 2 rays. FIFO vmcnt => chunk k ready at
// ~(k+1)/4 * T_mem; compiler's counted vmcnt before each chunk's setup waits
// only that prefix. Chunk0 compute starts ~3.5us; wall ~ T_mem/4 + T_compute
// ~ 22-25us. asm-"memory" pin after the load block forbids sinking.
//
// Predicted: VGPR 52-64 (peak = 36 pending raw + 6 state + acc), WRITE <=kB,
// FETCH ~49-50MB, rod ~24-30us, VALUBusy 60-75%, absmax 0.0.
// If FLAT vs R13 (~37): FIFO-prefix overlap theory dead -> oversubscribe grid
// or declare the additive floor.
//
// Codegen notes (hard-won, R2-R15):
//  - Loads issued BETWEEN compute phases get SUNK (R15, VGPR 40). Loads must
//    be issued in one contiguous block at the top.
//  - NEVER hold pipeline state in aggregates returned from branchy lambdas:
//    alloca -> scratch (R14, 24MB WRITE).
//  - Strided ray->lane map + float3 = compulsory-only transactions (R13 win).
//  - scalar iterate (4 fma + 2 mul + 1 rcp per ray) is the proven shape; no
//    double-rate packed fp32 on gfx950. global_load_lds staging kills MLP.
//  - No-spill signature: FETCH ~49-50MB, WRITE ~32-128B.
//  - Clamp(+-1000) provably inactive; rcp ~1ulp fine (absmax 0.0, R2-R15).

#define LM_ITERS 31
constexpr float DAMPING = 0.5f;

struct F3 { float x, y, z; };   // 12B, 4-aligned -> global_load_dwordx3

__global__ __launch_bounds__(256) void rod_kernel(
    const float* __restrict__ P, const float* __restrict__ V,
    const float* __restrict__ Rm, const float* __restrict__ Tv,
    const float* __restrict__ c_ptr, double* __restrict__ ws, int n)
{
    const float c  = c_ptr[0];
    const float r00 = Rm[0], r01 = Rm[1], r02 = Rm[2];
    const float r10 = Rm[3], r11 = Rm[4], r12 = Rm[5];
    const float r20 = Rm[6], r21 = Rm[7], r22 = Rm[8];
    const float t0 = Tv[0], t1 = Tv[1], t2 = Tv[2];

    const int lane = threadIdx.x & 63;
    const int wave = threadIdx.x >> 6;
    // wave owns 512 consecutive rays; lane's 8 rays strided (64*r + lane) so
    // every load instr reads a 768B lane-contiguous window (R13-proven).
    const int wbase = (blockIdx.x * 4 + wave) * 512;

    const F3* __restrict__ P3 = (const F3*)P;
    const F3* __restrict__ V3 = (const F3*)V;

    float px[8], py[8], pz[8], vx[8], vy[8], vz[8];

    if (wbase + 512 <= n) {
        // ---- ALL loads upfront, in CHUNK order (P then V per 2-ray chunk).
        // Contiguous issue block = nothing to sink; FIFO vmcnt gives prefix
        // completion per chunk.
        #pragma unroll
        for (int ck = 0; ck < 4; ++ck) {
            #pragma unroll
            for (int j = 0; j < 2; ++j) {
                const int r = 2 * ck + j;
                const F3 p = P3[wbase + 64 * r + lane];
                px[r] = p.x; py[r] = p.y; pz[r] = p.z;
            }
            #pragma unroll
            for (int j = 0; j < 2; ++j) {
                const int r = 2 * ck + j;
                const F3 v = V3[wbase + 64 * r + lane];
                vx[r] = v.x; vy[r] = v.y; vz[r] = v.z;
            }
        }
    } else {
        // tail fallback (not hit for n = 4M): guarded scalar loads
        #pragma unroll
        for (int r = 0; r < 8; ++r) {
            const int ray = wbase + 64 * r + lane;
            if (ray < n) {
                px[r] = P[3 * ray + 0]; py[r] = P[3 * ray + 1]; pz[r] = P[3 * ray + 2];
                vx[r] = V[3 * ray + 0]; vy[r] = V[3 * ray + 1]; vz[r] = V[3 * ray + 2];
            } else {
                px[r] = py[r] = pz[r] = 0.0f;
                vx[r] = vy[r] = vz[r] = 0.0f;
            }
        }
    }
    // Pin: no memory op may be moved below this point's position relative to
    // the compute that follows -- i.e. loads cannot be sunk into the chunks.
    asm volatile("" ::: "memory");

    double acc = 0.0;
    float nA[8], f[8], fp[8];

    // ---- chunked consumption: setup(2) -> iterate31(2) -> accum(2), x4.
    // Counted vmcnt before each chunk's setup waits only that chunk's prefix.
    #pragma unroll
    for (int ck = 0; ck < 4; ++ck) {
        #pragma unroll
        for (int j = 0; j < 2; ++j) {
            const int r = 2 * ck + j;
            const float ax = px[r] - t0, ay = py[r] - t1, az = pz[r] - t2;
            const float plx = ax * r00 + ay * r10 + az * r20;
            const float ply = ax * r01 + ay * r11 + az * r21;
            const float plz = ax * r02 + ay * r12 + az * r22;
            const float vlx = vx[r] * r00 + vy[r] * r10 + vz[r] * r20;
            const float vly = vx[r] * r01 + vy[r] * r11 + vz[r] * r21;
            const float vlz = vx[r] * r02 + vy[r] * r12 + vz[r] * r22;
            nA[r] = c * (vly * vly + vlz * vlz);                 // -A
            f[r]  = plx - c * (ply * ply + plz * plz);           // f(0)  = C
            fp[r] = vlx - 2.0f * c * (ply * vly + plz * vlz);    // f'(0) = B
        }
        // delta = f*f'/(f'^2+damping); tmp = f' - A*delta;
        // f <- f - delta*tmp (exact quadratic); f' <- tmp - A*delta.
        #pragma unroll 1
        for (int it = 0; it < LM_ITERS; ++it) {
            #pragma unroll
            for (int j = 0; j < 2; ++j) {
                const int r = 2 * ck + j;
                const float den = fmaf(fp[r], fp[r], DAMPING);
                const float rcp = __builtin_amdgcn_rcpf(den);  // ~1 ulp; LM self-corrects
                const float d   = (f[r] * fp[r]) * rcp;
                const float tmp = fmaf(nA[r], d, fp[r]);
                f[r]  = fmaf(-d, tmp, f[r]);
                fp[r] = fmaf(nA[r], d, tmp);
            }
        }
        #pragma unroll
        for (int j = 0; j < 2; ++j) {
            const int r = 2 * ck + j;
            if (wbase + 64 * r + lane < n)
                acc += (double)f[r] * (double)f[r];
        }
    }

    // wave(64) shuffle reduce -> LDS across 4 waves -> one f64 atomic per block
    for (int off = 32; off > 0; off >>= 1)
        acc += __shfl_down(acc, off, 64);
    __shared__ double sacc[4];
    if (lane == 0) sacc[wave] = acc;
    __syncthreads();
    if (threadIdx.x == 0) {
        atomicAdd(ws, sacc[0] + sacc[1] + sacc[2] + sacc[3]);
    }
}

__global__ void rod_finalize(const double* __restrict__ ws,
                             const float* __restrict__ loss_in,
                             float* __restrict__ out, double inv_n)
{
    out[0] = (float)(ws[0] * inv_n + (double)loss_in[0]);
}

extern "C" void kernel_launch(void* const* d_in, const int* in_sizes, int n_in,
                              void* d_out, int out_size, void* d_ws, size_t ws_size,
                              hipStream_t stream) {
    const float* P       = (const float*)d_in[0];
    const float* V       = (const float*)d_in[1];
    const float* R       = (const float*)d_in[2];
    const float* T       = (const float*)d_in[3];
    const float* c       = (const float*)d_in[4];
    const float* loss_in = (const float*)d_in[5];

    const int n = in_sizes[0] / 3;           // number of rays

    // d_ws is poisoned to 0xAA before every launch — zero the accumulator.
    hipMemsetAsync(d_ws, 0, sizeof(double), stream);

    // 8 rays/thread, 512 rays/wave, loads all upfront (chunk-ordered),
    // consumption in 4 chunks of 2 rays. 2048 blocks = 8 blocks/CU = whole
    // grid co-resident in one dispatch round.
    const int threads = (n + 7) / 8;
    const int block   = 256;
    const int grid    = (threads + block - 1) / block;
    rod_kernel<<<grid, block, 0, stream>>>(P, V, R, T, c, (double*)d_ws, n);
    rod_finalize<<<1, 1, 0, stream>>>((const double*)d_ws, loss_in,
                                      (float*)d_out, 1.0 / (double)n);
}